// Round 15
// baseline (478.821 us; speedup 1.0000x reference)
//
#include <hip/hip_runtime.h>
#include <cstdint>
#include <cstddef>

typedef __bf16 bf16_t;
using bf16x8 = __attribute__((ext_vector_type(8))) __bf16;
using f32x4  = __attribute__((ext_vector_type(4))) float;
using u16x4  = __attribute__((ext_vector_type(4))) unsigned short;

#define DEV __device__ __forceinline__

DEV void gload16(const void* g, void* l) {
  __builtin_amdgcn_global_load_lds((const __attribute__((address_space(1))) void*)g,
                                   (__attribute__((address_space(3))) void*)l, 16, 0, 0);
}

// ---------------------------------------------------------------- rope table
__global__ __launch_bounds__(256) void rope_table_kernel(float* cs) {
  int idx = blockIdx.x * 256 + threadIdx.x;
  if (idx >= 2048 * 64) return;
  int n = idx >> 6, d = idx & 63;
  int i = d & 31;
  float freq = (float)n * powf(10000.0f, -(float)i * (1.0f / 32.0f));
  cs[idx]          = cosf(freq);
  cs[131072 + idx] = sinf(freq);
}

// ------------------------------------------------- transpose+convert weights
__global__ __launch_bounds__(256) void transpose_cvt_kernel(
    const float* __restrict__ in, bf16_t* __restrict__ out,
    int R, int C, int ostride, int coff)
{
  __shared__ bf16_t T[64][80];
  const int c0 = blockIdx.x * 64, r0 = blockIdx.y * 64;
  const int t = threadIdx.x;
  const int lr = t >> 4;
  const int lc = (t & 15) * 4;
#pragma unroll
  for (int i = 0; i < 4; i++) {
    int r = lr + i * 16;
    float4 v = *(const float4*)(in + (size_t)(r0 + r) * C + c0 + lc);
    T[lc + 0][r] = (bf16_t)v.x;
    T[lc + 1][r] = (bf16_t)v.y;
    T[lc + 2][r] = (bf16_t)v.z;
    T[lc + 3][r] = (bf16_t)v.w;
  }
  __syncthreads();
  const int oc = t >> 2;
  const int rc = (t & 3) * 16;
  bf16_t* dst = out + (size_t)(c0 + oc) * ostride + coff + r0 + rc;
  *(bf16x8*)dst       = *(const bf16x8*)&T[oc][rc];
  *(bf16x8*)(dst + 8) = *(const bf16x8*)&T[oc][rc + 8];
}

// ------------------------------------------------------------------ RMSNorm
__global__ __launch_bounds__(256) void rmsnorm_kernel(
    const float* __restrict__ x, const float* __restrict__ g, bf16_t* __restrict__ xn)
{
  const int rid = blockIdx.x;
  const int t = threadIdx.x;
  const float* xr = x + (size_t)rid * 2048;
  float4 v0 = *(const float4*)(xr + t * 8);
  float4 v1 = *(const float4*)(xr + t * 8 + 4);
  float ss = v0.x*v0.x + v0.y*v0.y + v0.z*v0.z + v0.w*v0.w
           + v1.x*v1.x + v1.y*v1.y + v1.z*v1.z + v1.w*v1.w;
#pragma unroll
  for (int m = 1; m < 64; m <<= 1) ss += __shfl_xor(ss, m);
  __shared__ float red[4];
  if ((t & 63) == 0) red[t >> 6] = ss;
  __syncthreads();
  float tot = red[0] + red[1] + red[2] + red[3];
  float norm = sqrtf(tot * (1.0f / 2048.0f));
  float inv = 1.0f / fmaxf(norm, 1e-8f);
  float4 g0 = *(const float4*)(g + t * 8);
  float4 g1 = *(const float4*)(g + t * 8 + 4);
  bf16x8 o;
  o[0] = (bf16_t)(v0.x * inv * g0.x);
  o[1] = (bf16_t)(v0.y * inv * g0.y);
  o[2] = (bf16_t)(v0.z * inv * g0.z);
  o[3] = (bf16_t)(v0.w * inv * g0.w);
  o[4] = (bf16_t)(v1.x * inv * g1.x);
  o[5] = (bf16_t)(v1.y * inv * g1.y);
  o[6] = (bf16_t)(v1.z * inv * g1.z);
  o[7] = (bf16_t)(v1.w * inv * g1.w);
  *(bf16x8*)(xn + (size_t)rid * 2048 + t * 8) = o;
}

// -------------------------------------------------------------------- GEMM
// m97-structure (verified r12/r14 best). 1-D grid, bijective XCD chunking +
// BANDM-m-tile band ordering (A-band L2-resident). EPI 0 fuses
// bias+rope/split/gelu; EPI 1 bias->f32.
template <int EPI, int NTN, int BANDM>
__global__ __launch_bounds__(256, 2) void gemm_kernel(
    const bf16_t* __restrict__ A, const bf16_t* __restrict__ Bt, int K,
    const float* __restrict__ bias0, const float* __restrict__ bias1,
    const float* __restrict__ cs,
    bf16_t* __restrict__ qr, bf16_t* __restrict__ kr, bf16_t* __restrict__ vt,
    bf16_t* __restrict__ out_ap, float* __restrict__ out_f)
{
  __shared__ bf16_t Ash[128 * 64];
  __shared__ bf16_t Bsh[128 * 64];
  const int tid = threadIdx.x;
  const int w = tid >> 6, lane = tid & 63;
  const int wr = w >> 1, wc = w & 1;
  const int nwg = gridDim.x;
  const int g2  = (blockIdx.x & 7) * (nwg >> 3) + (blockIdx.x >> 3);
  const int mt  = (g2 % BANDM) + (g2 / (BANDM * NTN)) * BANDM;
  const int nt  = (g2 / BANDM) % NTN;
  const int m0 = mt * 128, n0 = nt * 128;
  const int l15 = lane & 15, g4 = lane >> 4;

  f32x4 acc[4][4];
#pragma unroll
  for (int i = 0; i < 4; i++)
#pragma unroll
    for (int j = 0; j < 4; j++) acc[i][j] = f32x4{0.f, 0.f, 0.f, 0.f};

  for (int ks = 0; ks < K; ks += 64) {
    __syncthreads();
#pragma unroll
    for (int i = 0; i < 4; i++) {
      int slot = w * 256 + i * 64 + lane;
      int row = slot >> 3, ch = slot & 7;
      int gch = ch ^ (row & 7);
      gload16(A + (size_t)(m0 + row) * K + ks + gch * 8, (char*)Ash + (w * 4 + i) * 1024);
    }
#pragma unroll
    for (int i = 0; i < 4; i++) {
      int slot = w * 256 + i * 64 + lane;
      int row = slot >> 3, ch = slot & 7;
      int gch = ch ^ (row & 7);
      gload16(Bt + (size_t)(n0 + row) * K + ks + gch * 8, (char*)Bsh + (w * 4 + i) * 1024);
    }
    __syncthreads();
    const char* Ab = (const char*)Ash;
    const char* Bb = (const char*)Bsh;
#pragma unroll
    for (int kc = 0; kc < 2; kc++) {
      bf16x8 af[4], bfr[4];
#pragma unroll
      for (int mi = 0; mi < 4; mi++) {
        int r = wr * 64 + mi * 16 + l15;
        af[mi] = *(const bf16x8*)(Ab + r * 128 + ((kc * 64 + g4 * 16) ^ ((r & 7) << 4)));
      }
#pragma unroll
      for (int ni = 0; ni < 4; ni++) {
        int r = wc * 64 + ni * 16 + l15;
        bfr[ni] = *(const bf16x8*)(Bb + r * 128 + ((kc * 64 + g4 * 16) ^ ((r & 7) << 4)));
      }
#pragma unroll
      for (int mi = 0; mi < 4; mi++)
#pragma unroll
        for (int ni = 0; ni < 4; ni++)
          acc[mi][ni] = __builtin_amdgcn_mfma_f32_16x16x32_bf16(af[mi], bfr[ni], acc[mi][ni], 0, 0, 0);
    }
  }

#pragma unroll
  for (int mi = 0; mi < 4; mi++) {
    const int rb = m0 + wr * 64 + mi * 16 + g4 * 4;
#pragma unroll
    for (int ni = 0; ni < 4; ni++) {
      const int c = n0 + wc * 64 + ni * 16 + l15;
      if (EPI == 0) {
        if (n0 < 1024 || (n0 == 1024 && wc == 0)) {
          // rope (q if n0<1024 else k)
          const int d = ni * 16 + l15;
          const float bz  = bias0[c];
          const float bz2 = bias0[c ^ 32];
#pragma unroll
          for (int j = 0; j < 4; j++) {
            const int r = rb + j;
            const int n = r & 2047, bb = r >> 11;
            float v0 = acc[mi][ni][j] + bz;
            float vp = acc[mi][ni ^ 2][j] + bz2;
            float rot = (ni < 2) ? -vp : vp;
            float cv = cs[n * 64 + d];
            float sv = cs[131072 + n * 64 + d];
            float o = v0 * cv + rot * sv;
            if (n0 < 1024) {
              const int h = (n0 >> 6) + wc;
              qr[((size_t)(bb * 16 + h) * 2048 + n) * 64 + d] = (bf16_t)(o * 0.125f);
            } else {
              kr[((size_t)bb * 2048 + n) * 64 + d] = (bf16_t)o;
            }
          }
        } else if (n0 == 1024) {
          // v -> vt[b][d][n]
          const int d = ni * 16 + l15;
          const float bz = bias0[c];
          const int n4 = rb & 2047, bb = rb >> 11;
          u16x4 pw;
#pragma unroll
          for (int j = 0; j < 4; j++) {
            bf16_t pv = (bf16_t)(acc[mi][ni][j] + bz);
            pw[j] = __builtin_bit_cast(unsigned short, pv);
          }
          *(u16x4*)(vt + ((size_t)bb * 64 + d) * 2048 + n4) = pw;
        } else {
          const float bz = bias0[c];
#pragma unroll
          for (int j = 0; j < 4; j++) {
            float v = acc[mi][ni][j] + bz;
            float ge = 0.5f * v * (1.0f + erff(v * 0.70710678118f));
            out_ap[(size_t)(rb + j) * 9216 + (c - 128)] = (bf16_t)ge;
          }
        }
      } else {
        const float bz = bias0[c] + bias1[c];
#pragma unroll
        for (int j = 0; j < 4; j++)
          out_f[(size_t)(rb + j) * 2048 + c] = acc[mi][ni][j] + bz;
      }
    }
  }
}

// ---------------------------------------------------------------- attention
// 4 waves/block, 128 q-rows. Longest-first dispatch: blockIdx.x reversed so
// high-q0 (most kv-tiles, causal) blocks launch first -> balanced makespan.
__global__ __launch_bounds__(256) void attn_kernel(
    const bf16_t* __restrict__ qr, const bf16_t* __restrict__ kr,
    const bf16_t* __restrict__ vt, bf16_t* __restrict__ Ap)
{
  __shared__ bf16_t Ksh[64 * 64];
  __shared__ bf16_t Vsh[64 * 64];
  __shared__ bf16_t Psh[4][32 * 64];
  const int tid = threadIdx.x;
  const int w = tid >> 6, lane = tid & 63;
  const int l15 = lane & 15, g4 = lane >> 4;
  const int wun = tid & ~63;
  const int bh = blockIdx.y;
  const int b = bh >> 4, h = bh & 15;
  const int q0 = (gridDim.x - 1 - blockIdx.x) * 128;   // longest-first
  const int q0w = q0 + w * 32;

  bf16x8 bq[2][2];
  const bf16_t* qbase = qr + ((size_t)bh * 2048 + q0w) * 64;
#pragma unroll
  for (int qi = 0; qi < 2; qi++)
#pragma unroll
    for (int kc = 0; kc < 2; kc++)
      bq[qi][kc] = *(const bf16x8*)(qbase + (qi * 16 + l15) * 64 + kc * 32 + g4 * 8);

  const bf16_t* kb = kr + (size_t)b * 2048 * 64;
  const bf16_t* vb = vt + (size_t)b * 64 * 2048;

  f32x4 acc_o[2][4];
#pragma unroll
  for (int i = 0; i < 2; i++)
#pragma unroll
    for (int j = 0; j < 4; j++) acc_o[i][j] = f32x4{0.f, 0.f, 0.f, 0.f};
  float m_run[2] = {-1e30f, -1e30f};
  float l_run[2] = {0.f, 0.f};
  const int btlast = (q0 + 127) >> 6;
  const int wtlast = (q0w + 31) >> 6;

  for (int t = 0; t <= btlast; ++t) {
    const int kv0 = t * 64;
#pragma unroll
    for (int i = 0; i < 2; i++) {
      int slot = i * 256 + tid;
      int row = slot >> 3, ch = slot & 7;
      int gch = ch ^ (row & 7);
      gload16(kb + (size_t)(kv0 + row) * 64 + gch * 8, (char*)Ksh + (i * 256 + wun) * 16);
    }
#pragma unroll
    for (int i = 0; i < 2; i++) {
      int slot = i * 256 + tid;
      int row = slot >> 3, ch = slot & 7;   // row = d
      int gch = ch ^ (row & 7);
      gload16(vb + (size_t)row * 2048 + kv0 + gch * 8, (char*)Vsh + (i * 256 + wun) * 16);
    }
    __syncthreads();

    if (t <= wtlast) {
      f32x4 st[4][2];
#pragma unroll
      for (int i = 0; i < 4; i++)
#pragma unroll
        for (int j = 0; j < 2; j++) st[i][j] = f32x4{0.f, 0.f, 0.f, 0.f};
      const char* Kb8 = (const char*)Ksh;
#pragma unroll
      for (int kc = 0; kc < 2; kc++) {
        bf16x8 ak[4];
#pragma unroll
        for (int ni = 0; ni < 4; ni++) {
          int r = ni * 16 + l15;
          ak[ni] = *(const bf16x8*)(Kb8 + r * 128 + ((kc * 64 + g4 * 16) ^ ((r & 7) << 4)));
        }
#pragma unroll
        for (int ni = 0; ni < 4; ni++)
#pragma unroll
          for (int qi = 0; qi < 2; qi++)
            st[ni][qi] = __builtin_amdgcn_mfma_f32_16x16x32_bf16(ak[ni], bq[qi][kc], st[ni][qi], 0, 0, 0);
      }

      if (t == wtlast) {
#pragma unroll
        for (int ni = 0; ni < 4; ni++)
#pragma unroll
          for (int qi = 0; qi < 2; qi++)
#pragma unroll
            for (int j = 0; j < 4; j++) {
              int kv = kv0 + ni * 16 + g4 * 4 + j;
              int q  = q0w + qi * 16 + l15;
              if (kv > q) st[ni][qi][j] = -1e30f;
            }
      }

      float sc[2];
#pragma unroll
      for (int qi = 0; qi < 2; qi++) {
        float vm = -1e30f;
#pragma unroll
        for (int ni = 0; ni < 4; ni++)
#pragma unroll
          for (int j = 0; j < 4; j++) vm = fmaxf(vm, st[ni][qi][j]);
        vm = fmaxf(vm, __shfl_xor(vm, 16));
        vm = fmaxf(vm, __shfl_xor(vm, 32));
        float mn = fmaxf(m_run[qi], vm);
        sc[qi] = __expf(m_run[qi] - mn);
        float ps = 0.f;
#pragma unroll
        for (int ni = 0; ni < 4; ni++)
#pragma unroll
          for (int j = 0; j < 4; j++) {
            float p = __expf(st[ni][qi][j] - mn);
            st[ni][qi][j] = p;
            ps += p;
          }
        l_run[qi] = l_run[qi] * sc[qi] + ps;
        m_run[qi] = mn;
      }

#pragma unroll
      for (int mi = 0; mi < 2; mi++)
#pragma unroll
        for (int j = 0; j < 4; j++) {
          float f = __shfl(sc[mi], g4 * 4 + j);
#pragma unroll
          for (int nd = 0; nd < 4; nd++) acc_o[mi][nd][j] *= f;
        }

#pragma unroll
      for (int ni = 0; ni < 4; ni++)
#pragma unroll
        for (int qi = 0; qi < 2; qi++) {
          int q = qi * 16 + l15;
          int kv = ni * 16 + g4 * 4;
          u16x4 pw;
#pragma unroll
          for (int j = 0; j < 4; j++) {
            bf16_t pv = (bf16_t)st[ni][qi][j];
            pw[j] = __builtin_bit_cast(unsigned short, pv);
          }
          *(u16x4*)((char*)Psh[w] + q * 128 + ((kv * 2) ^ ((q & 7) << 4))) = pw;
        }

      const char* Pb8 = (const char*)Psh[w];
      const char* Vb8 = (const char*)Vsh;
#pragma unroll
      for (int kc = 0; kc < 2; kc++) {
        bf16x8 apf[2], bvf[4];
#pragma unroll
        for (int mi = 0; mi < 2; mi++) {
          int r = mi * 16 + l15;
          apf[mi] = *(const bf16x8*)(Pb8 + r * 128 + ((kc * 64 + g4 * 16) ^ ((r & 7) << 4)));
        }
#pragma unroll
        for (int nd = 0; nd < 4; nd++) {
          int r = nd * 16 + l15;
          bvf[nd] = *(const bf16x8*)(Vb8 + r * 128 + ((kc * 64 + g4 * 16) ^ ((r & 7) << 4)));
        }
#pragma unroll
        for (int mi = 0; mi < 2; mi++)
#pragma unroll
          for (int nd = 0; nd < 4; nd++)
            acc_o[mi][nd] = __builtin_amdgcn_mfma_f32_16x16x32_bf16(apf[mi], bvf[nd], acc_o[mi][nd], 0, 0, 0);
      }
    }
    __syncthreads();
  }

#pragma unroll
  for (int qi = 0; qi < 2; qi++) {
    float l = l_run[qi];
    l += __shfl_xor(l, 16);
    l += __shfl_xor(l, 32);
    l_run[qi] = l;
  }
#pragma unroll
  for (int mi = 0; mi < 2; mi++)
#pragma unroll
    for (int j = 0; j < 4; j++) {
      float linv = 1.0f / __shfl(l_run[mi], g4 * 4 + j);
      int r = q0w + mi * 16 + g4 * 4 + j;
      bf16_t* orow = Ap + (size_t)(b * 2048 + r) * 9216 + h * 64;
#pragma unroll
      for (int nd = 0; nd < 4; nd++)
        orow[nd * 16 + l15] = (bf16_t)(acc_o[mi][nd][j] * linv);
    }
}

// ------------------------------------------------------------------- launch
extern "C" void kernel_launch(void* const* d_in, const int* in_sizes, int n_in,
                              void* d_out, int out_size, void* d_ws, size_t ws_size,
                              hipStream_t stream)
{
  const float* x       = (const float*)d_in[0];
  const float* g       = (const float*)d_in[1];
  const float* W_fused = (const float*)d_in[2];
  const float* b_fused = (const float*)d_in[3];
  const float* W_attn  = (const float*)d_in[4];
  const float* b_attn  = (const float*)d_in[5];
  const float* W_ff    = (const float*)d_in[6];
  const float* b_ff    = (const float*)d_in[7];
  float* out = (float*)d_out;
  char* ws = (char*)d_ws;

  bf16_t* Wf_t = (bf16_t*)(ws + 0);            // [9344][2048]   38,273,024
  bf16_t* xn   = (bf16_t*)(ws + 38273024);     // [4096][2048]   -> 55,050,240
  bf16_t* qr   = (bf16_t*)(ws + 55050240);     // [32][2048][64] -> 63,438,848
  bf16_t* kr   = (bf16_t*)(ws + 63438848);     // [2][2048][64]  -> 63,963,136
  bf16_t* vt   = (bf16_t*)(ws + 63963136);     // [2][64][2048]  -> 64,487,424
  float*  cs   = (float*)(ws + 64487424);      // cos|sin        -> 65,536,000
  bf16_t* Wc_t = (bf16_t*)(ws + 65536000);     // [2048][9216]   -> 103,284,736
  bf16_t* Ap   = (bf16_t*)(ws + 103284736);    // [4096][9216]   -> 178,782,208

  rope_table_kernel<<<512, 256, 0, stream>>>(cs);
  transpose_cvt_kernel<<<dim3(146, 32), 256, 0, stream>>>(W_fused, Wf_t, 2048, 9344, 2048, 0);
  transpose_cvt_kernel<<<dim3(32, 16),  256, 0, stream>>>(W_attn,  Wc_t, 1024, 2048, 9216, 0);
  transpose_cvt_kernel<<<dim3(32, 128), 256, 0, stream>>>(W_ff,    Wc_t, 8192, 2048, 9216, 1024);
  rmsnorm_kernel<<<4096, 256, 0, stream>>>(x, g, xn);
  // GEMM1 (+fused bias/rope/split/gelu): 73 n x 32 m = 2336 blocks, BANDM=8
  gemm_kernel<0, 73, 8><<<2336, 256, 0, stream>>>(xn, Wf_t, 2048, b_fused, nullptr, cs,
                                                  qr, kr, vt, Ap, nullptr);
  attn_kernel<<<dim3(16, 32), 256, 0, stream>>>(qr, kr, vt, Ap);
  // GEMM2: 16 n x 32 m = 512 blocks, BANDM=2 (A-band 4.7 MB ~ L2)
  gemm_kernel<1, 16, 2><<<512, 256, 0, stream>>>(Ap, Wc_t, 9216, b_attn, b_ff, nullptr,
                                                 nullptr, nullptr, nullptr, nullptr, out);
}

// Round 16
// 472.512 us; speedup vs baseline: 1.0134x; 1.0134x over previous
//
#include <hip/hip_runtime.h>
#include <cstdint>
#include <cstddef>

typedef __bf16 bf16_t;
using bf16x8 = __attribute__((ext_vector_type(8))) __bf16;
using f32x4  = __attribute__((ext_vector_type(4))) float;
using u16x4  = __attribute__((ext_vector_type(4))) unsigned short;

#define DEV __device__ __forceinline__

DEV void gload16(const void* g, void* l) {
  __builtin_amdgcn_global_load_lds((const __attribute__((address_space(1))) void*)g,
                                   (__attribute__((address_space(3))) void*)l, 16, 0, 0);
}

// ---------------------------------------------------------------- rope table
__global__ __launch_bounds__(256) void rope_table_kernel(float* cs) {
  for (int idx = blockIdx.x * 256 + threadIdx.x; idx < 2048 * 64; idx += 256 * 256) {
    int n = idx >> 6, d = idx & 63;
    int i = d & 31;
    float freq = (float)n * powf(10000.0f, -(float)i * (1.0f / 32.0f));
    cs[idx]          = cosf(freq);
    cs[131072 + idx] = sinf(freq);
  }
}

// ------------------------------------------------- transpose+convert weights
// out[c][coff + r] = (bf16) in[r][c];  out row stride = ostride
DEV void transpose_tile(const float* in, bf16_t* out, int C, int ostride,
                        int coff, int c0, int r0, int t) {
  __shared__ bf16_t T[64][80];
  const int lr = t >> 4;
  const int lc = (t & 15) * 4;
#pragma unroll
  for (int i = 0; i < 4; i++) {
    int r = lr + i * 16;
    float4 v = *(const float4*)(in + (size_t)(r0 + r) * C + c0 + lc);
    T[lc + 0][r] = (bf16_t)v.x;
    T[lc + 1][r] = (bf16_t)v.y;
    T[lc + 2][r] = (bf16_t)v.z;
    T[lc + 3][r] = (bf16_t)v.w;
  }
  __syncthreads();
  const int oc = t >> 2;
  const int rc = (t & 3) * 16;
  bf16_t* dst = out + (size_t)(c0 + oc) * ostride + coff + r0 + rc;
  *(bf16x8*)dst       = *(const bf16x8*)&T[oc][rc];
  *(bf16x8*)(dst + 8) = *(const bf16x8*)&T[oc][rc + 8];
}

__global__ __launch_bounds__(256) void transpose_cvt_kernel(
    const float* __restrict__ in, bf16_t* __restrict__ out,
    int C, int ostride, int coff)
{
  transpose_tile(in, out, C, ostride, coff, blockIdx.x * 64, blockIdx.y * 64,
                 threadIdx.x);
}

// merged W_attn (by<16) + W_ff (by>=16) -> Wc_t
__global__ __launch_bounds__(256) void transpose_cvt2_kernel(
    const float* __restrict__ inA, const float* __restrict__ inF,
    bf16_t* __restrict__ out)
{
  const int by = blockIdx.y;
  if (by < 16)
    transpose_tile(inA, out, 2048, 9216, 0,    blockIdx.x * 64, by * 64, threadIdx.x);
  else
    transpose_tile(inF, out, 2048, 9216, 1024, blockIdx.x * 64, (by - 16) * 64, threadIdx.x);
}

// ------------------------------------------------------------------ RMSNorm
__global__ __launch_bounds__(256) void rmsnorm_kernel(
    const float* __restrict__ x, const float* __restrict__ g, bf16_t* __restrict__ xn)
{
  const int rid = blockIdx.x;
  const int t = threadIdx.x;
  const float* xr = x + (size_t)rid * 2048;
  float4 v0 = *(const float4*)(xr + t * 8);
  float4 v1 = *(const float4*)(xr + t * 8 + 4);
  float ss = v0.x*v0.x + v0.y*v0.y + v0.z*v0.z + v0.w*v0.w
           + v1.x*v1.x + v1.y*v1.y + v1.z*v1.z + v1.w*v1.w;
#pragma unroll
  for (int m = 1; m < 64; m <<= 1) ss += __shfl_xor(ss, m);
  __shared__ float red[4];
  if ((t & 63) == 0) red[t >> 6] = ss;
  __syncthreads();
  float tot = red[0] + red[1] + red[2] + red[3];
  float norm = sqrtf(tot * (1.0f / 2048.0f));
  float inv = 1.0f / fmaxf(norm, 1e-8f);
  float4 g0 = *(const float4*)(g + t * 8);
  float4 g1 = *(const float4*)(g + t * 8 + 4);
  bf16x8 o;
  o[0] = (bf16_t)(v0.x * inv * g0.x);
  o[1] = (bf16_t)(v0.y * inv * g0.y);
  o[2] = (bf16_t)(v0.z * inv * g0.z);
  o[3] = (bf16_t)(v0.w * inv * g0.w);
  o[4] = (bf16_t)(v1.x * inv * g1.x);
  o[5] = (bf16_t)(v1.y * inv * g1.y);
  o[6] = (bf16_t)(v1.z * inv * g1.z);
  o[7] = (bf16_t)(v1.w * inv * g1.w);
  *(bf16x8*)(xn + (size_t)rid * 2048 + t * 8) = o;
}

// -------------------------------------------------------------------- GEMM
// m97-structure (verified best). 1-D grid, bijective XCD chunking + BANDM
// band ordering (A-band L2-resident). EPI 0 fuses bias+rope/split/gelu;
// EPI 1 bias->f32.
template <int EPI, int NTN, int BANDM>
__global__ __launch_bounds__(256, 2) void gemm_kernel(
    const bf16_t* __restrict__ A, const bf16_t* __restrict__ Bt, int K,
    const float* __restrict__ bias0, const float* __restrict__ bias1,
    const float* __restrict__ cs,
    bf16_t* __restrict__ qr, bf16_t* __restrict__ kr, bf16_t* __restrict__ vt,
    bf16_t* __restrict__ out_ap, float* __restrict__ out_f)
{
  __shared__ bf16_t Ash[128 * 64];
  __shared__ bf16_t Bsh[128 * 64];
  const int tid = threadIdx.x;
  const int w = tid >> 6, lane = tid & 63;
  const int wr = w >> 1, wc = w & 1;
  const int nwg = gridDim.x;
  const int g2  = (blockIdx.x & 7) * (nwg >> 3) + (blockIdx.x >> 3);
  const int mt  = (g2 % BANDM) + (g2 / (BANDM * NTN)) * BANDM;
  const int nt  = (g2 / BANDM) % NTN;
  const int m0 = mt * 128, n0 = nt * 128;
  const int l15 = lane & 15, g4 = lane >> 4;

  f32x4 acc[4][4];
#pragma unroll
  for (int i = 0; i < 4; i++)
#pragma unroll
    for (int j = 0; j < 4; j++) acc[i][j] = f32x4{0.f, 0.f, 0.f, 0.f};

  for (int ks = 0; ks < K; ks += 64) {
    __syncthreads();
#pragma unroll
    for (int i = 0; i < 4; i++) {
      int slot = w * 256 + i * 64 + lane;
      int row = slot >> 3, ch = slot & 7;
      int gch = ch ^ (row & 7);
      gload16(A + (size_t)(m0 + row) * K + ks + gch * 8, (char*)Ash + (w * 4 + i) * 1024);
    }
#pragma unroll
    for (int i = 0; i < 4; i++) {
      int slot = w * 256 + i * 64 + lane;
      int row = slot >> 3, ch = slot & 7;
      int gch = ch ^ (row & 7);
      gload16(Bt + (size_t)(n0 + row) * K + ks + gch * 8, (char*)Bsh + (w * 4 + i) * 1024);
    }
    __syncthreads();
    const char* Ab = (const char*)Ash;
    const char* Bb = (const char*)Bsh;
#pragma unroll
    for (int kc = 0; kc < 2; kc++) {
      bf16x8 af[4], bfr[4];
#pragma unroll
      for (int mi = 0; mi < 4; mi++) {
        int r = wr * 64 + mi * 16 + l15;
        af[mi] = *(const bf16x8*)(Ab + r * 128 + ((kc * 64 + g4 * 16) ^ ((r & 7) << 4)));
      }
#pragma unroll
      for (int ni = 0; ni < 4; ni++) {
        int r = wc * 64 + ni * 16 + l15;
        bfr[ni] = *(const bf16x8*)(Bb + r * 128 + ((kc * 64 + g4 * 16) ^ ((r & 7) << 4)));
      }
#pragma unroll
      for (int mi = 0; mi < 4; mi++)
#pragma unroll
        for (int ni = 0; ni < 4; ni++)
          acc[mi][ni] = __builtin_amdgcn_mfma_f32_16x16x32_bf16(af[mi], bfr[ni], acc[mi][ni], 0, 0, 0);
    }
  }

#pragma unroll
  for (int mi = 0; mi < 4; mi++) {
    const int rb = m0 + wr * 64 + mi * 16 + g4 * 4;
#pragma unroll
    for (int ni = 0; ni < 4; ni++) {
      const int c = n0 + wc * 64 + ni * 16 + l15;
      if (EPI == 0) {
        if (n0 < 1024 || (n0 == 1024 && wc == 0)) {
          // rope (q if n0<1024 else k)
          const int d = ni * 16 + l15;
          const float bz  = bias0[c];
          const float bz2 = bias0[c ^ 32];
#pragma unroll
          for (int j = 0; j < 4; j++) {
            const int r = rb + j;
            const int n = r & 2047, bb = r >> 11;
            float v0 = acc[mi][ni][j] + bz;
            float vp = acc[mi][ni ^ 2][j] + bz2;
            float rot = (ni < 2) ? -vp : vp;
            float cv = cs[n * 64 + d];
            float sv = cs[131072 + n * 64 + d];
            float o = v0 * cv + rot * sv;
            if (n0 < 1024) {
              const int h = (n0 >> 6) + wc;
              qr[((size_t)(bb * 16 + h) * 2048 + n) * 64 + d] = (bf16_t)(o * 0.125f);
            } else {
              kr[((size_t)bb * 2048 + n) * 64 + d] = (bf16_t)o;
            }
          }
        } else if (n0 == 1024) {
          // v -> vt[b][d][n]
          const int d = ni * 16 + l15;
          const float bz = bias0[c];
          const int n4 = rb & 2047, bb = rb >> 11;
          u16x4 pw;
#pragma unroll
          for (int j = 0; j < 4; j++) {
            bf16_t pv = (bf16_t)(acc[mi][ni][j] + bz);
            pw[j] = __builtin_bit_cast(unsigned short, pv);
          }
          *(u16x4*)(vt + ((size_t)bb * 64 + d) * 2048 + n4) = pw;
        } else {
          const float bz = bias0[c];
#pragma unroll
          for (int j = 0; j < 4; j++) {
            float v = acc[mi][ni][j] + bz;
            float ge = 0.5f * v * (1.0f + erff(v * 0.70710678118f));
            out_ap[(size_t)(rb + j) * 9216 + (c - 128)] = (bf16_t)ge;
          }
        }
      } else {
        const float bz = bias0[c] + bias1[c];
#pragma unroll
        for (int j = 0; j < 4; j++)
          out_f[(size_t)(rb + j) * 2048 + c] = acc[mi][ni][j] + bz;
      }
    }
  }
}

// ---------------------------------------------------------------- attention
// 4 waves/block, 128 q-rows. Longest-first dispatch (reversed blockIdx.x).
__global__ __launch_bounds__(256) void attn_kernel(
    const bf16_t* __restrict__ qr, const bf16_t* __restrict__ kr,
    const bf16_t* __restrict__ vt, bf16_t* __restrict__ Ap)
{
  __shared__ bf16_t Ksh[64 * 64];
  __shared__ bf16_t Vsh[64 * 64];
  __shared__ bf16_t Psh[4][32 * 64];
  const int tid = threadIdx.x;
  const int w = tid >> 6, lane = tid & 63;
  const int l15 = lane & 15, g4 = lane >> 4;
  const int wun = tid & ~63;
  const int bh = blockIdx.y;
  const int b = bh >> 4, h = bh & 15;
  const int q0 = (gridDim.x - 1 - blockIdx.x) * 128;
  const int q0w = q0 + w * 32;

  bf16x8 bq[2][2];
  const bf16_t* qbase = qr + ((size_t)bh * 2048 + q0w) * 64;
#pragma unroll
  for (int qi = 0; qi < 2; qi++)
#pragma unroll
    for (int kc = 0; kc < 2; kc++)
      bq[qi][kc] = *(const bf16x8*)(qbase + (qi * 16 + l15) * 64 + kc * 32 + g4 * 8);

  const bf16_t* kb = kr + (size_t)b * 2048 * 64;
  const bf16_t* vb = vt + (size_t)b * 64 * 2048;

  f32x4 acc_o[2][4];
#pragma unroll
  for (int i = 0; i < 2; i++)
#pragma unroll
    for (int j = 0; j < 4; j++) acc_o[i][j] = f32x4{0.f, 0.f, 0.f, 0.f};
  float m_run[2] = {-1e30f, -1e30f};
  float l_run[2] = {0.f, 0.f};
  const int btlast = (q0 + 127) >> 6;
  const int wtlast = (q0w + 31) >> 6;

  for (int t = 0; t <= btlast; ++t) {
    const int kv0 = t * 64;
#pragma unroll
    for (int i = 0; i < 2; i++) {
      int slot = i * 256 + tid;
      int row = slot >> 3, ch = slot & 7;
      int gch = ch ^ (row & 7);
      gload16(kb + (size_t)(kv0 + row) * 64 + gch * 8, (char*)Ksh + (i * 256 + wun) * 16);
    }
#pragma unroll
    for (int i = 0; i < 2; i++) {
      int slot = i * 256 + tid;
      int row = slot >> 3, ch = slot & 7;   // row = d
      int gch = ch ^ (row & 7);
      gload16(vb + (size_t)row * 2048 + kv0 + gch * 8, (char*)Vsh + (i * 256 + wun) * 16);
    }
    __syncthreads();

    if (t <= wtlast) {
      f32x4 st[4][2];
#pragma unroll
      for (int i = 0; i < 4; i++)
#pragma unroll
        for (int j = 0; j < 2; j++) st[i][j] = f32x4{0.f, 0.f, 0.f, 0.f};
      const char* Kb8 = (const char*)Ksh;
#pragma unroll
      for (int kc = 0; kc < 2; kc++) {
        bf16x8 ak[4];
#pragma unroll
        for (int ni = 0; ni < 4; ni++) {
          int r = ni * 16 + l15;
          ak[ni] = *(const bf16x8*)(Kb8 + r * 128 + ((kc * 64 + g4 * 16) ^ ((r & 7) << 4)));
        }
#pragma unroll
        for (int ni = 0; ni < 4; ni++)
#pragma unroll
          for (int qi = 0; qi < 2; qi++)
            st[ni][qi] = __builtin_amdgcn_mfma_f32_16x16x32_bf16(ak[ni], bq[qi][kc], st[ni][qi], 0, 0, 0);
      }

      if (t == wtlast) {
#pragma unroll
        for (int ni = 0; ni < 4; ni++)
#pragma unroll
          for (int qi = 0; qi < 2; qi++)
#pragma unroll
            for (int j = 0; j < 4; j++) {
              int kv = kv0 + ni * 16 + g4 * 4 + j;
              int q  = q0w + qi * 16 + l15;
              if (kv > q) st[ni][qi][j] = -1e30f;
            }
      }

      float sc[2];
#pragma unroll
      for (int qi = 0; qi < 2; qi++) {
        float vm = -1e30f;
#pragma unroll
        for (int ni = 0; ni < 4; ni++)
#pragma unroll
          for (int j = 0; j < 4; j++) vm = fmaxf(vm, st[ni][qi][j]);
        vm = fmaxf(vm, __shfl_xor(vm, 16));
        vm = fmaxf(vm, __shfl_xor(vm, 32));
        float mn = fmaxf(m_run[qi], vm);
        sc[qi] = __expf(m_run[qi] - mn);
        float ps = 0.f;
#pragma unroll
        for (int ni = 0; ni < 4; ni++)
#pragma unroll
          for (int j = 0; j < 4; j++) {
            float p = __expf(st[ni][qi][j] - mn);
            st[ni][qi][j] = p;
            ps += p;
          }
        l_run[qi] = l_run[qi] * sc[qi] + ps;
        m_run[qi] = mn;
      }

#pragma unroll
      for (int mi = 0; mi < 2; mi++)
#pragma unroll
        for (int j = 0; j < 4; j++) {
          float f = __shfl(sc[mi], g4 * 4 + j);
#pragma unroll
          for (int nd = 0; nd < 4; nd++) acc_o[mi][nd][j] *= f;
        }

#pragma unroll
      for (int ni = 0; ni < 4; ni++)
#pragma unroll
        for (int qi = 0; qi < 2; qi++) {
          int q = qi * 16 + l15;
          int kv = ni * 16 + g4 * 4;
          u16x4 pw;
#pragma unroll
          for (int j = 0; j < 4; j++) {
            bf16_t pv = (bf16_t)st[ni][qi][j];
            pw[j] = __builtin_bit_cast(unsigned short, pv);
          }
          *(u16x4*)((char*)Psh[w] + q * 128 + ((kv * 2) ^ ((q & 7) << 4))) = pw;
        }

      const char* Pb8 = (const char*)Psh[w];
      const char* Vb8 = (const char*)Vsh;
#pragma unroll
      for (int kc = 0; kc < 2; kc++) {
        bf16x8 apf[2], bvf[4];
#pragma unroll
        for (int mi = 0; mi < 2; mi++) {
          int r = mi * 16 + l15;
          apf[mi] = *(const bf16x8*)(Pb8 + r * 128 + ((kc * 64 + g4 * 16) ^ ((r & 7) << 4)));
        }
#pragma unroll
        for (int nd = 0; nd < 4; nd++) {
          int r = nd * 16 + l15;
          bvf[nd] = *(const bf16x8*)(Vb8 + r * 128 + ((kc * 64 + g4 * 16) ^ ((r & 7) << 4)));
        }
#pragma unroll
        for (int mi = 0; mi < 2; mi++)
#pragma unroll
          for (int nd = 0; nd < 4; nd++)
            acc_o[mi][nd] = __builtin_amdgcn_mfma_f32_16x16x32_bf16(apf[mi], bvf[nd], acc_o[mi][nd], 0, 0, 0);
      }
    }
    __syncthreads();
  }

#pragma unroll
  for (int qi = 0; qi < 2; qi++) {
    float l = l_run[qi];
    l += __shfl_xor(l, 16);
    l += __shfl_xor(l, 32);
    l_run[qi] = l;
  }
#pragma unroll
  for (int mi = 0; mi < 2; mi++)
#pragma unroll
    for (int j = 0; j < 4; j++) {
      float linv = 1.0f / __shfl(l_run[mi], g4 * 4 + j);
      int r = q0w + mi * 16 + g4 * 4 + j;
      bf16_t* orow = Ap + (size_t)(b * 2048 + r) * 9216 + h * 64;
#pragma unroll
      for (int nd = 0; nd < 4; nd++)
        orow[nd * 16 + l15] = (bf16_t)(acc_o[mi][nd][j] * linv);
    }
}

// ------------------------------------------------------------------- launch
extern "C" void kernel_launch(void* const* d_in, const int* in_sizes, int n_in,
                              void* d_out, int out_size, void* d_ws, size_t ws_size,
                              hipStream_t stream)
{
  const float* x       = (const float*)d_in[0];
  const float* g       = (const float*)d_in[1];
  const float* W_fused = (const float*)d_in[2];
  const float* b_fused = (const float*)d_in[3];
  const float* W_attn  = (const float*)d_in[4];
  const float* b_attn  = (const float*)d_in[5];
  const float* W_ff    = (const float*)d_in[6];
  const float* b_ff    = (const float*)d_in[7];
  float* out = (float*)d_out;
  char* ws = (char*)d_ws;

  bf16_t* Wf_t = (bf16_t*)(ws + 0);            // [9344][2048]   38,273,024
  bf16_t* xn   = (bf16_t*)(ws + 38273024);     // [4096][2048]   -> 55,050,240
  bf16_t* qr   = (bf16_t*)(ws + 55050240);     // [32][2048][64] -> 63,438,848
  bf16_t* kr   = (bf16_t*)(ws + 63438848);     // [2][2048][64]  -> 63,963,136
  bf16_t* vt   = (bf16_t*)(ws + 63963136);     // [2][64][2048]  -> 64,487,424
  float*  cs   = (float*)(ws + 64487424);      // cos|sin        -> 65,536,000
  bf16_t* Wc_t = (bf16_t*)(ws + 65536000);     // [2048][9216]   -> 103,284,736
  bf16_t* Ap   = (bf16_t*)(ws + 103284736);    // [4096][9216]   -> 178,782,208

  rope_table_kernel<<<256, 256, 0, stream>>>(cs);
  transpose_cvt_kernel<<<dim3(146, 32), 256, 0, stream>>>(W_fused, Wf_t, 9344, 2048, 0);
  transpose_cvt2_kernel<<<dim3(32, 144), 256, 0, stream>>>(W_attn, W_ff, Wc_t);
  rmsnorm_kernel<<<4096, 256, 0, stream>>>(x, g, xn);
  // GEMM1 (+fused bias/rope/split/gelu): 73 n x 32 m = 2336 blocks, BANDM=8
  gemm_kernel<0, 73, 8><<<2336, 256, 0, stream>>>(xn, Wf_t, 2048, b_fused, nullptr, cs,
                                                  qr, kr, vt, Ap, nullptr);
  attn_kernel<<<dim3(16, 32), 256, 0, stream>>>(qr, kr, vt, Ap);
  // GEMM2: 16 n x 32 m = 512 blocks, BANDM=2 (A-band 4.7 MB ~ L2)
  gemm_kernel<1, 16, 2><<<512, 256, 0, stream>>>(Ap, Wc_t, 9216, b_attn, b_ff, nullptr,
                                                 nullptr, nullptr, nullptr, nullptr, out);
}

// Round 17
// 471.638 us; speedup vs baseline: 1.0152x; 1.0019x over previous
//
#include <hip/hip_runtime.h>
#include <cstdint>
#include <cstddef>

typedef __bf16 bf16_t;
using bf16x8 = __attribute__((ext_vector_type(8))) __bf16;
using f32x4  = __attribute__((ext_vector_type(4))) float;
using u16x4  = __attribute__((ext_vector_type(4))) unsigned short;

#define DEV __device__ __forceinline__

DEV void gload16(const void* g, void* l) {
  __builtin_amdgcn_global_load_lds((const __attribute__((address_space(1))) void*)g,
                                   (__attribute__((address_space(3))) void*)l, 16, 0, 0);
}

// ---------------------------------------------------------------- rope table
__global__ __launch_bounds__(256) void rope_table_kernel(float* cs) {
  for (int idx = blockIdx.x * 256 + threadIdx.x; idx < 2048 * 64; idx += 256 * 256) {
    int n = idx >> 6, d = idx & 63;
    int i = d & 31;
    float freq = (float)n * powf(10000.0f, -(float)i * (1.0f / 32.0f));
    cs[idx]          = cosf(freq);
    cs[131072 + idx] = sinf(freq);
  }
}

// ------------------------------------------------- transpose+convert weights
// out[c][coff + r] = (bf16) in[r][c];  out row stride = ostride
DEV void transpose_tile(const float* in, bf16_t* out, int C, int ostride,
                        int coff, int c0, int r0, int t) {
  __shared__ bf16_t T[64][80];
  const int lr = t >> 4;
  const int lc = (t & 15) * 4;
#pragma unroll
  for (int i = 0; i < 4; i++) {
    int r = lr + i * 16;
    float4 v = *(const float4*)(in + (size_t)(r0 + r) * C + c0 + lc);
    T[lc + 0][r] = (bf16_t)v.x;
    T[lc + 1][r] = (bf16_t)v.y;
    T[lc + 2][r] = (bf16_t)v.z;
    T[lc + 3][r] = (bf16_t)v.w;
  }
  __syncthreads();
  const int oc = t >> 2;
  const int rc = (t & 3) * 16;
  bf16_t* dst = out + (size_t)(c0 + oc) * ostride + coff + r0 + rc;
  *(bf16x8*)dst       = *(const bf16x8*)&T[oc][rc];
  *(bf16x8*)(dst + 8) = *(const bf16x8*)&T[oc][rc + 8];
}

__global__ __launch_bounds__(256) void transpose_cvt_kernel(
    const float* __restrict__ in, bf16_t* __restrict__ out,
    int C, int ostride, int coff)
{
  transpose_tile(in, out, C, ostride, coff, blockIdx.x * 64, blockIdx.y * 64,
                 threadIdx.x);
}

// merged W_attn (by<16) + W_ff (by>=16) -> Wc_t
__global__ __launch_bounds__(256) void transpose_cvt2_kernel(
    const float* __restrict__ inA, const float* __restrict__ inF,
    bf16_t* __restrict__ out)
{
  const int by = blockIdx.y;
  if (by < 16)
    transpose_tile(inA, out, 2048, 9216, 0,    blockIdx.x * 64, by * 64, threadIdx.x);
  else
    transpose_tile(inF, out, 2048, 9216, 1024, blockIdx.x * 64, (by - 16) * 64, threadIdx.x);
}

// ------------------------------------------------------------------ RMSNorm
__global__ __launch_bounds__(256) void rmsnorm_kernel(
    const float* __restrict__ x, const float* __restrict__ g, bf16_t* __restrict__ xn)
{
  const int rid = blockIdx.x;
  const int t = threadIdx.x;
  const float* xr = x + (size_t)rid * 2048;
  float4 v0 = *(const float4*)(xr + t * 8);
  float4 v1 = *(const float4*)(xr + t * 8 + 4);
  float ss = v0.x*v0.x + v0.y*v0.y + v0.z*v0.z + v0.w*v0.w
           + v1.x*v1.x + v1.y*v1.y + v1.z*v1.z + v1.w*v1.w;
#pragma unroll
  for (int m = 1; m < 64; m <<= 1) ss += __shfl_xor(ss, m);
  __shared__ float red[4];
  if ((t & 63) == 0) red[t >> 6] = ss;
  __syncthreads();
  float tot = red[0] + red[1] + red[2] + red[3];
  float norm = sqrtf(tot * (1.0f / 2048.0f));
  float inv = 1.0f / fmaxf(norm, 1e-8f);
  float4 g0 = *(const float4*)(g + t * 8);
  float4 g1 = *(const float4*)(g + t * 8 + 4);
  bf16x8 o;
  o[0] = (bf16_t)(v0.x * inv * g0.x);
  o[1] = (bf16_t)(v0.y * inv * g0.y);
  o[2] = (bf16_t)(v0.z * inv * g0.z);
  o[3] = (bf16_t)(v0.w * inv * g0.w);
  o[4] = (bf16_t)(v1.x * inv * g1.x);
  o[5] = (bf16_t)(v1.y * inv * g1.y);
  o[6] = (bf16_t)(v1.z * inv * g1.z);
  o[7] = (bf16_t)(v1.w * inv * g1.w);
  *(bf16x8*)(xn + (size_t)rid * 2048 + t * 8) = o;
}

// -------------------------------------------------------------------- GEMM
// m97-structure (verified best). 1-D grid, bijective XCD chunking + BANDM
// band ordering (A-band L2-resident). launch_bounds(256,4): unified regs
// capped at 128 (current use 124) -> 4 blocks/CU resident (LDS 4x32=128KB),
// +33% waves to hide the barrier drain. EPI 0 fuses bias+rope/split/gelu;
// EPI 1 bias->f32.
template <int EPI, int NTN, int BANDM>
__global__ __launch_bounds__(256, 4) void gemm_kernel(
    const bf16_t* __restrict__ A, const bf16_t* __restrict__ Bt, int K,
    const float* __restrict__ bias0, const float* __restrict__ bias1,
    const float* __restrict__ cs,
    bf16_t* __restrict__ qr, bf16_t* __restrict__ kr, bf16_t* __restrict__ vt,
    bf16_t* __restrict__ out_ap, float* __restrict__ out_f)
{
  __shared__ bf16_t Ash[128 * 64];
  __shared__ bf16_t Bsh[128 * 64];
  const int tid = threadIdx.x;
  const int w = tid >> 6, lane = tid & 63;
  const int wr = w >> 1, wc = w & 1;
  const int nwg = gridDim.x;
  const int g2  = (blockIdx.x & 7) * (nwg >> 3) + (blockIdx.x >> 3);
  const int mt  = (g2 % BANDM) + (g2 / (BANDM * NTN)) * BANDM;
  const int nt  = (g2 / BANDM) % NTN;
  const int m0 = mt * 128, n0 = nt * 128;
  const int l15 = lane & 15, g4 = lane >> 4;

  f32x4 acc[4][4];
#pragma unroll
  for (int i = 0; i < 4; i++)
#pragma unroll
    for (int j = 0; j < 4; j++) acc[i][j] = f32x4{0.f, 0.f, 0.f, 0.f};

  for (int ks = 0; ks < K; ks += 64) {
    __syncthreads();
#pragma unroll
    for (int i = 0; i < 4; i++) {
      int slot = w * 256 + i * 64 + lane;
      int row = slot >> 3, ch = slot & 7;
      int gch = ch ^ (row & 7);
      gload16(A + (size_t)(m0 + row) * K + ks + gch * 8, (char*)Ash + (w * 4 + i) * 1024);
    }
#pragma unroll
    for (int i = 0; i < 4; i++) {
      int slot = w * 256 + i * 64 + lane;
      int row = slot >> 3, ch = slot & 7;
      int gch = ch ^ (row & 7);
      gload16(Bt + (size_t)(n0 + row) * K + ks + gch * 8, (char*)Bsh + (w * 4 + i) * 1024);
    }
    __syncthreads();
    const char* Ab = (const char*)Ash;
    const char* Bb = (const char*)Bsh;
#pragma unroll
    for (int kc = 0; kc < 2; kc++) {
      bf16x8 af[4], bfr[4];
#pragma unroll
      for (int mi = 0; mi < 4; mi++) {
        int r = wr * 64 + mi * 16 + l15;
        af[mi] = *(const bf16x8*)(Ab + r * 128 + ((kc * 64 + g4 * 16) ^ ((r & 7) << 4)));
      }
#pragma unroll
      for (int ni = 0; ni < 4; ni++) {
        int r = wc * 64 + ni * 16 + l15;
        bfr[ni] = *(const bf16x8*)(Bb + r * 128 + ((kc * 64 + g4 * 16) ^ ((r & 7) << 4)));
      }
#pragma unroll
      for (int mi = 0; mi < 4; mi++)
#pragma unroll
        for (int ni = 0; ni < 4; ni++)
          acc[mi][ni] = __builtin_amdgcn_mfma_f32_16x16x32_bf16(af[mi], bfr[ni], acc[mi][ni], 0, 0, 0);
    }
  }

#pragma unroll
  for (int mi = 0; mi < 4; mi++) {
    const int rb = m0 + wr * 64 + mi * 16 + g4 * 4;
#pragma unroll
    for (int ni = 0; ni < 4; ni++) {
      const int c = n0 + wc * 64 + ni * 16 + l15;
      if (EPI == 0) {
        if (n0 < 1024 || (n0 == 1024 && wc == 0)) {
          // rope (q if n0<1024 else k)
          const int d = ni * 16 + l15;
          const float bz  = bias0[c];
          const float bz2 = bias0[c ^ 32];
#pragma unroll
          for (int j = 0; j < 4; j++) {
            const int r = rb + j;
            const int n = r & 2047, bb = r >> 11;
            float v0 = acc[mi][ni][j] + bz;
            float vp = acc[mi][ni ^ 2][j] + bz2;
            float rot = (ni < 2) ? -vp : vp;
            float cv = cs[n * 64 + d];
            float sv = cs[131072 + n * 64 + d];
            float o = v0 * cv + rot * sv;
            if (n0 < 1024) {
              const int h = (n0 >> 6) + wc;
              qr[((size_t)(bb * 16 + h) * 2048 + n) * 64 + d] = (bf16_t)(o * 0.125f);
            } else {
              kr[((size_t)bb * 2048 + n) * 64 + d] = (bf16_t)o;
            }
          }
        } else if (n0 == 1024) {
          // v -> vt[b][d][n]
          const int d = ni * 16 + l15;
          const float bz = bias0[c];
          const int n4 = rb & 2047, bb = rb >> 11;
          u16x4 pw;
#pragma unroll
          for (int j = 0; j < 4; j++) {
            bf16_t pv = (bf16_t)(acc[mi][ni][j] + bz);
            pw[j] = __builtin_bit_cast(unsigned short, pv);
          }
          *(u16x4*)(vt + ((size_t)bb * 64 + d) * 2048 + n4) = pw;
        } else {
          const float bz = bias0[c];
#pragma unroll
          for (int j = 0; j < 4; j++) {
            float v = acc[mi][ni][j] + bz;
            float ge = 0.5f * v * (1.0f + erff(v * 0.70710678118f));
            out_ap[(size_t)(rb + j) * 9216 + (c - 128)] = (bf16_t)ge;
          }
        }
      } else {
        const float bz = bias0[c] + bias1[c];
#pragma unroll
        for (int j = 0; j < 4; j++)
          out_f[(size_t)(rb + j) * 2048 + c] = acc[mi][ni][j] + bz;
      }
    }
  }
}

// ---------------------------------------------------------------- attention
// 4 waves/block, 128 q-rows. Longest-first dispatch (reversed blockIdx.x).
__global__ __launch_bounds__(256) void attn_kernel(
    const bf16_t* __restrict__ qr, const bf16_t* __restrict__ kr,
    const bf16_t* __restrict__ vt, bf16_t* __restrict__ Ap)
{
  __shared__ bf16_t Ksh[64 * 64];
  __shared__ bf16_t Vsh[64 * 64];
  __shared__ bf16_t Psh[4][32 * 64];
  const int tid = threadIdx.x;
  const int w = tid >> 6, lane = tid & 63;
  const int l15 = lane & 15, g4 = lane >> 4;
  const int wun = tid & ~63;
  const int bh = blockIdx.y;
  const int b = bh >> 4, h = bh & 15;
  const int q0 = (gridDim.x - 1 - blockIdx.x) * 128;
  const int q0w = q0 + w * 32;

  bf16x8 bq[2][2];
  const bf16_t* qbase = qr + ((size_t)bh * 2048 + q0w) * 64;
#pragma unroll
  for (int qi = 0; qi < 2; qi++)
#pragma unroll
    for (int kc = 0; kc < 2; kc++)
      bq[qi][kc] = *(const bf16x8*)(qbase + (qi * 16 + l15) * 64 + kc * 32 + g4 * 8);

  const bf16_t* kb = kr + (size_t)b * 2048 * 64;
  const bf16_t* vb = vt + (size_t)b * 64 * 2048;

  f32x4 acc_o[2][4];
#pragma unroll
  for (int i = 0; i < 2; i++)
#pragma unroll
    for (int j = 0; j < 4; j++) acc_o[i][j] = f32x4{0.f, 0.f, 0.f, 0.f};
  float m_run[2] = {-1e30f, -1e30f};
  float l_run[2] = {0.f, 0.f};
  const int btlast = (q0 + 127) >> 6;
  const int wtlast = (q0w + 31) >> 6;

  for (int t = 0; t <= btlast; ++t) {
    const int kv0 = t * 64;
#pragma unroll
    for (int i = 0; i < 2; i++) {
      int slot = i * 256 + tid;
      int row = slot >> 3, ch = slot & 7;
      int gch = ch ^ (row & 7);
      gload16(kb + (size_t)(kv0 + row) * 64 + gch * 8, (char*)Ksh + (i * 256 + wun) * 16);
    }
#pragma unroll
    for (int i = 0; i < 2; i++) {
      int slot = i * 256 + tid;
      int row = slot >> 3, ch = slot & 7;   // row = d
      int gch = ch ^ (row & 7);
      gload16(vb + (size_t)row * 2048 + kv0 + gch * 8, (char*)Vsh + (i * 256 + wun) * 16);
    }
    __syncthreads();

    if (t <= wtlast) {
      f32x4 st[4][2];
#pragma unroll
      for (int i = 0; i < 4; i++)
#pragma unroll
        for (int j = 0; j < 2; j++) st[i][j] = f32x4{0.f, 0.f, 0.f, 0.f};
      const char* Kb8 = (const char*)Ksh;
#pragma unroll
      for (int kc = 0; kc < 2; kc++) {
        bf16x8 ak[4];
#pragma unroll
        for (int ni = 0; ni < 4; ni++) {
          int r = ni * 16 + l15;
          ak[ni] = *(const bf16x8*)(Kb8 + r * 128 + ((kc * 64 + g4 * 16) ^ ((r & 7) << 4)));
        }
#pragma unroll
        for (int ni = 0; ni < 4; ni++)
#pragma unroll
          for (int qi = 0; qi < 2; qi++)
            st[ni][qi] = __builtin_amdgcn_mfma_f32_16x16x32_bf16(ak[ni], bq[qi][kc], st[ni][qi], 0, 0, 0);
      }

      if (t == wtlast) {
#pragma unroll
        for (int ni = 0; ni < 4; ni++)
#pragma unroll
          for (int qi = 0; qi < 2; qi++)
#pragma unroll
            for (int j = 0; j < 4; j++) {
              int kv = kv0 + ni * 16 + g4 * 4 + j;
              int q  = q0w + qi * 16 + l15;
              if (kv > q) st[ni][qi][j] = -1e30f;
            }
      }

      float sc[2];
#pragma unroll
      for (int qi = 0; qi < 2; qi++) {
        float vm = -1e30f;
#pragma unroll
        for (int ni = 0; ni < 4; ni++)
#pragma unroll
          for (int j = 0; j < 4; j++) vm = fmaxf(vm, st[ni][qi][j]);
        vm = fmaxf(vm, __shfl_xor(vm, 16));
        vm = fmaxf(vm, __shfl_xor(vm, 32));
        float mn = fmaxf(m_run[qi], vm);
        sc[qi] = __expf(m_run[qi] - mn);
        float ps = 0.f;
#pragma unroll
        for (int ni = 0; ni < 4; ni++)
#pragma unroll
          for (int j = 0; j < 4; j++) {
            float p = __expf(st[ni][qi][j] - mn);
            st[ni][qi][j] = p;
            ps += p;
          }
        l_run[qi] = l_run[qi] * sc[qi] + ps;
        m_run[qi] = mn;
      }

#pragma unroll
      for (int mi = 0; mi < 2; mi++)
#pragma unroll
        for (int j = 0; j < 4; j++) {
          float f = __shfl(sc[mi], g4 * 4 + j);
#pragma unroll
          for (int nd = 0; nd < 4; nd++) acc_o[mi][nd][j] *= f;
        }

#pragma unroll
      for (int ni = 0; ni < 4; ni++)
#pragma unroll
        for (int qi = 0; qi < 2; qi++) {
          int q = qi * 16 + l15;
          int kv = ni * 16 + g4 * 4;
          u16x4 pw;
#pragma unroll
          for (int j = 0; j < 4; j++) {
            bf16_t pv = (bf16_t)st[ni][qi][j];
            pw[j] = __builtin_bit_cast(unsigned short, pv);
          }
          *(u16x4*)((char*)Psh[w] + q * 128 + ((kv * 2) ^ ((q & 7) << 4))) = pw;
        }

      const char* Pb8 = (const char*)Psh[w];
      const char* Vb8 = (const char*)Vsh;
#pragma unroll
      for (int kc = 0; kc < 2; kc++) {
        bf16x8 apf[2], bvf[4];
#pragma unroll
        for (int mi = 0; mi < 2; mi++) {
          int r = mi * 16 + l15;
          apf[mi] = *(const bf16x8*)(Pb8 + r * 128 + ((kc * 64 + g4 * 16) ^ ((r & 7) << 4)));
        }
#pragma unroll
        for (int nd = 0; nd < 4; nd++) {
          int r = nd * 16 + l15;
          bvf[nd] = *(const bf16x8*)(Vb8 + r * 128 + ((kc * 64 + g4 * 16) ^ ((r & 7) << 4)));
        }
#pragma unroll
        for (int mi = 0; mi < 2; mi++)
#pragma unroll
          for (int nd = 0; nd < 4; nd++)
            acc_o[mi][nd] = __builtin_amdgcn_mfma_f32_16x16x32_bf16(apf[mi], bvf[nd], acc_o[mi][nd], 0, 0, 0);
      }
    }
    __syncthreads();
  }

#pragma unroll
  for (int qi = 0; qi < 2; qi++) {
    float l = l_run[qi];
    l += __shfl_xor(l, 16);
    l += __shfl_xor(l, 32);
    l_run[qi] = l;
  }
#pragma unroll
  for (int mi = 0; mi < 2; mi++)
#pragma unroll
    for (int j = 0; j < 4; j++) {
      float linv = 1.0f / __shfl(l_run[mi], g4 * 4 + j);
      int r = q0w + mi * 16 + g4 * 4 + j;
      bf16_t* orow = Ap + (size_t)(b * 2048 + r) * 9216 + h * 64;
#pragma unroll
      for (int nd = 0; nd < 4; nd++)
        orow[nd * 16 + l15] = (bf16_t)(acc_o[mi][nd][j] * linv);
    }
}

// ------------------------------------------------------------------- launch
extern "C" void kernel_launch(void* const* d_in, const int* in_sizes, int n_in,
                              void* d_out, int out_size, void* d_ws, size_t ws_size,
                              hipStream_t stream)
{
  const float* x       = (const float*)d_in[0];
  const float* g       = (const float*)d_in[1];
  const float* W_fused = (const float*)d_in[2];
  const float* b_fused = (const float*)d_in[3];
  const float* W_attn  = (const float*)d_in[4];
  const float* b_attn  = (const float*)d_in[5];
  const float* W_ff    = (const float*)d_in[6];
  const float* b_ff    = (const float*)d_in[7];
  float* out = (float*)d_out;
  char* ws = (char*)d_ws;

  bf16_t* Wf_t = (bf16_t*)(ws + 0);            // [9344][2048]   38,273,024
  bf16_t* xn   = (bf16_t*)(ws + 38273024);     // [4096][2048]   -> 55,050,240
  bf16_t* qr   = (bf16_t*)(ws + 55050240);     // [32][2048][64] -> 63,438,848
  bf16_t* kr   = (bf16_t*)(ws + 63438848);     // [2][2048][64]  -> 63,963,136
  bf16_t* vt   = (bf16_t*)(ws + 63963136);     // [2][64][2048]  -> 64,487,424
  float*  cs   = (float*)(ws + 64487424);      // cos|sin        -> 65,536,000
  bf16_t* Wc_t = (bf16_t*)(ws + 65536000);     // [2048][9216]   -> 103,284,736
  bf16_t* Ap   = (bf16_t*)(ws + 103284736);    // [4096][9216]   -> 178,782,208

  rope_table_kernel<<<256, 256, 0, stream>>>(cs);
  transpose_cvt_kernel<<<dim3(146, 32), 256, 0, stream>>>(W_fused, Wf_t, 9344, 2048, 0);
  transpose_cvt2_kernel<<<dim3(32, 144), 256, 0, stream>>>(W_attn, W_ff, Wc_t);
  rmsnorm_kernel<<<4096, 256, 0, stream>>>(x, g, xn);
  // GEMM1 (+fused bias/rope/split/gelu): 73 n x 32 m = 2336 blocks, BANDM=8
  gemm_kernel<0, 73, 8><<<2336, 256, 0, stream>>>(xn, Wf_t, 2048, b_fused, nullptr, cs,
                                                  qr, kr, vt, Ap, nullptr);
  attn_kernel<<<dim3(16, 32), 256, 0, stream>>>(qr, kr, vt, Ap);
  // GEMM2: 16 n x 32 m = 512 blocks, BANDM=2 (A-band 4.7 MB ~ L2)
  gemm_kernel<1, 16, 2><<<512, 256, 0, stream>>>(Ap, Wc_t, 9216, b_attn, b_ff, nullptr,
                                                 nullptr, nullptr, nullptr, nullptr, out);
}